// Round 19
// baseline (87.657 us; speedup 1.0000x reference)
//
#include <hip/hip_runtime.h>
#include <hip/hip_bf16.h>

using f32x4  = __attribute__((ext_vector_type(4))) float;
using bf16x8 = __attribute__((ext_vector_type(8))) __bf16;
using u16x8  = __attribute__((ext_vector_type(8))) unsigned short;

#define QSCALE 0.18033688f   // 0.125 * log2(e): scores pre-scaled into exp2 domain

static __device__ __forceinline__ unsigned short f2bf(float f) {
    unsigned u = __builtin_bit_cast(unsigned, f);
    u += 0x7FFF + ((u >> 16) & 1);   // RNE
    return (unsigned short)(u >> 16);
}

static __device__ __forceinline__ float fexp2(float x) {
    float r;
    asm("v_exp_f32 %0, %1" : "=v"(r) : "v"(x));
    return r;
}

static __device__ __forceinline__ u16x8 pk8(f32x4 a, f32x4 b) {
    u16x8 o;
    o[0] = __builtin_bit_cast(unsigned short, (__bf16)a.x);
    o[1] = __builtin_bit_cast(unsigned short, (__bf16)a.y);
    o[2] = __builtin_bit_cast(unsigned short, (__bf16)a.z);
    o[3] = __builtin_bit_cast(unsigned short, (__bf16)a.w);
    o[4] = __builtin_bit_cast(unsigned short, (__bf16)b.x);
    o[5] = __builtin_bit_cast(unsigned short, (__bf16)b.y);
    o[6] = __builtin_bit_cast(unsigned short, (__bf16)b.z);
    o[7] = __builtin_bit_cast(unsigned short, (__bf16)b.w);
    return o;
}

static __device__ __forceinline__ void gload_lds16(const unsigned short* g, unsigned short* l) {
    __builtin_amdgcn_global_load_lds(
        (const __attribute__((address_space(1))) unsigned int*)g,
        (__attribute__((address_space(3))) unsigned int*)l, 16, 0, 0);
}

// ---------------------------------------------------------------------------
// Kernel 0: fp32 -> bf16 convert — WEIGHTS ONLY.
// ---------------------------------------------------------------------------
__global__ __launch_bounds__(256) void cvt3(
    const float* __restrict__ s0, const float* __restrict__ s1, const float* __restrict__ s2,
    unsigned short* __restrict__ d0, unsigned short* __restrict__ d1, unsigned short* __restrict__ d2)
{
    const int y = blockIdx.y;
    const float* s = y == 0 ? s0 : y == 1 ? s1 : s2;
    unsigned short* d = y == 0 ? d0 : y == 1 ? d1 : d2;
    const int n = 1024 * 1024;
    const int stride = gridDim.x * 256 * 8;
    for (int i = (blockIdx.x * 256 + threadIdx.x) * 8; i < n; i += stride) {
        f32x4 a = *(const f32x4*)(s + i);
        f32x4 b = *(const f32x4*)(s + i + 4);
        *(u16x8*)(d + i) = pk8(a, b);
    }
}

// ---------------------------------------------------------------------------
// Kernel 1 (fused fp32->bf16 A-path, DEPTH-2 on both paths):
// Y = X_fp32 @ W_bf16^T + bias. 128x128 tile, 4 waves, BK=32.
// As double-buffered (16 KiB), Bs TRI-buffered (24 KiB). Per iteration kt:
//   T0 (kt>=1): cvt a(kt) regs (loaded at S1(kt-2): 2-iter cover) -> As[kt&1]
//   S1 load a(kt+2) fp32 -> regs
//   S2 issue B(kt+2) global_load_lds -> Bs[(kt+2)%3]
//   S3 vmcnt(12) = count of loads newer than B(kt)
//      (B(kt+1)2 + a(kt+1)4 + a(kt+2)4 + B(kt+2)2) -> retires B(kt) only;
//      B now has 2 iterations of latency cover (was 1 -> the ~1000cyc floor)
//   S4 lgkmcnt(0)+s_barrier; S5 16 MFMA; S7 lgkmcnt(0)+s_barrier
// No wait ever precedes the MFMAs except 2-iter-old data (r17 bug avoided).
// which = blockIdx.y; which==0 (Q) xQSCALE. XCD-chunked block swizzle.
// ---------------------------------------------------------------------------
__global__ __launch_bounds__(256) void gemm_bt(
    const float* __restrict__ X0, const float* __restrict__ X1, const float* __restrict__ X2,
    const unsigned short* __restrict__ B0, const unsigned short* __restrict__ B1, const unsigned short* __restrict__ B2,
    const float* __restrict__ b0, const float* __restrict__ b1, const float* __restrict__ b2,
    unsigned short* __restrict__ O0, unsigned short* __restrict__ O1, unsigned short* __restrict__ O2)
{
    const int N = 1024, K = 1024;
    const int which = blockIdx.y;
    const float* X = which == 0 ? X0 : (which == 1 ? X1 : X2);
    const unsigned short* B = which == 0 ? B0 : (which == 1 ? B1 : B2);
    const float* bias = which == 0 ? b0 : (which == 1 ? b1 : b2);
    unsigned short* O = which == 0 ? O0 : (which == 1 ? O1 : O2);

    const int xs = (blockIdx.x & 7) * 32 + (blockIdx.x >> 3);   // bijective XCD chunking
    const int bm = xs >> 3;
    const int bn = xs & 7;
    const int row0 = bm * 128, col0 = bn * 128;

    __shared__ __align__(16) unsigned short As[2 * 4096];
    __shared__ __align__(16) unsigned short Bs[3 * 4096];

    const int t = threadIdx.x;
    const int lane = t & 63;
    const int wave = t >> 6;
    const int wr = (wave >> 1) * 64, wc = (wave & 1) * 64;
    const int fr = lane & 15;
    const int fq = lane >> 4;

    f32x4 acc[4][4] = {};

    const int r0s = t >> 2, k0s = (t & 3) * 8;
    const int r1s = (t + 256) >> 2;
    const int dB0 = (wave * 64) * 8;
    const int dB1 = (256 + wave * 64) * 8;

    const float* Xa0 = X + (size_t)(row0 + r0s) * K + k0s;
    const float* Xa1 = X + (size_t)(row0 + r1s) * K + k0s;
    const unsigned short* Bb0 = B + (size_t)(col0 + r0s) * K + k0s;
    const unsigned short* Bb1 = B + (size_t)(col0 + r1s) * K + k0s;
    unsigned short* wA0 = &As[r0s * 32 + k0s];
    unsigned short* wA1 = &As[r1s * 32 + k0s];

    // prologue: A(0) direct (load+write), B(0)->Bs[0], B(1)->Bs[1], rL=a(1)
    f32x4 rW0, rW1, rW2, rW3;   // a(kt)   at loop top (write at T0)
    f32x4 rL0, rL1, rL2, rL3;   // a(kt+1) at loop top
    {
        f32x4 p0 = *(const f32x4*)(Xa0);
        f32x4 p1 = *(const f32x4*)(Xa0 + 4);
        f32x4 p2 = *(const f32x4*)(Xa1);
        f32x4 p3 = *(const f32x4*)(Xa1 + 4);
        gload_lds16(Bb0, &Bs[dB0]);
        gload_lds16(Bb1, &Bs[dB1]);
        gload_lds16(Bb0 + 32, &Bs[4096 + dB0]);
        gload_lds16(Bb1 + 32, &Bs[4096 + dB1]);
        rL0 = *(const f32x4*)(Xa0 + 32);
        rL1 = *(const f32x4*)(Xa0 + 36);
        rL2 = *(const f32x4*)(Xa1 + 32);
        rL3 = *(const f32x4*)(Xa1 + 36);
        *(u16x8*)(wA0) = pk8(p0, p1);    // compiler inserts wait for p-regs
        *(u16x8*)(wA1) = pk8(p2, p3);
    }

    int bRo = 0, bWo = 2 * 4096;   // Bs read/write element offsets (cycle 0,4096,8192)
    for (int kt = 0; kt < 32; ++kt) {
        // T0: write a(kt) (loaded 2 iterations ago) into As[kt&1]
        if (kt >= 1) {
            const int aOff = (kt & 1) * 4096;
            *(u16x8*)(wA0 + aOff) = pk8(rW0, rW1);
            *(u16x8*)(wA1 + aOff) = pk8(rW2, rW3);
        }
        f32x4 rT0, rT1, rT2, rT3;
        if (kt + 2 < 32) {
            // S1: a(kt+2) -> regs
            const int kn2 = (kt + 2) * 32;
            rT0 = *(const f32x4*)(Xa0 + kn2);
            rT1 = *(const f32x4*)(Xa0 + kn2 + 4);
            rT2 = *(const f32x4*)(Xa1 + kn2);
            rT3 = *(const f32x4*)(Xa1 + kn2 + 4);
            // S2: B(kt+2) -> Bs[bWo]
            gload_lds16(Bb0 + kn2, &Bs[bWo + dB0]);
            gload_lds16(Bb1 + kn2, &Bs[bWo + dB1]);
        }
        // S3: retire exactly B(kt); everything newer stays in flight
        if (kt <= 29)      asm volatile("s_waitcnt vmcnt(12)" ::: "memory");
        else if (kt == 30) asm volatile("s_waitcnt vmcnt(6)"  ::: "memory");
        else               asm volatile("s_waitcnt vmcnt(0)"  ::: "memory");
        __builtin_amdgcn_sched_barrier(0);
        // S4: drain T0 ds_writes; sync
        asm volatile("s_waitcnt lgkmcnt(0)" ::: "memory");
        __builtin_amdgcn_s_barrier();

        // S5: compute tile kt
        const int aOff = (kt & 1) * 4096;
        bf16x8 af[4], bfr[4];
        #pragma unroll
        for (int m = 0; m < 4; ++m)
            af[m] = *(const bf16x8*)(&As[aOff + (wr + m * 16 + fr) * 32 + fq * 8]);
        #pragma unroll
        for (int n = 0; n < 4; ++n)
            bfr[n] = *(const bf16x8*)(&Bs[bRo + (wc + n * 16 + fr) * 32 + fq * 8]);
        __builtin_amdgcn_s_setprio(1);
        #pragma unroll
        for (int m = 0; m < 4; ++m)
            #pragma unroll
            for (int n = 0; n < 4; ++n)
                acc[m][n] = __builtin_amdgcn_mfma_f32_16x16x32_bf16(af[m], bfr[n], acc[m][n], 0, 0, 0);
        __builtin_amdgcn_s_setprio(0);

        // S7: release buffers
        asm volatile("s_waitcnt lgkmcnt(0)" ::: "memory");
        __builtin_amdgcn_sched_barrier(0);
        __builtin_amdgcn_s_barrier();

        rW0 = rL0; rW1 = rL1; rW2 = rL2; rW3 = rL3;
        rL0 = rT0; rL1 = rT1; rL2 = rT2; rL3 = rT3;
        bRo = (bRo == 2 * 4096) ? 0 : bRo + 4096;
        bWo = (bWo == 2 * 4096) ? 0 : bWo + 4096;
    }

    const float sc = (which == 0) ? QSCALE : 1.0f;
    #pragma unroll
    for (int n = 0; n < 4; ++n) {
        const int col = col0 + wc + n * 16 + fr;
        const float bv = bias[col];
        #pragma unroll
        for (int m = 0; m < 4; ++m) {
            #pragma unroll
            for (int r = 0; r < 4; ++r) {
                const int row = row0 + wr + m * 16 + fq * 4 + r;
                O[(size_t)row * N + col] = f2bf((acc[m][n][r] + bv) * sc);
            }
        }
    }
}

// ---------------------------------------------------------------------------
// Kernel 1b: V[b*S+s][h*64+dk] -> Vt[(b*16+h)*64+dk][s]. LDS 64x72 tile.
// ---------------------------------------------------------------------------
__global__ __launch_bounds__(256) void vtrans(
    const unsigned short* __restrict__ V, unsigned short* __restrict__ Vt)
{
    const int S = 1024, Dm = 1024;
    const int sb = blockIdx.x;
    const int h = blockIdx.y, b = blockIdx.z;
    __shared__ __align__(16) unsigned short Lt[64][72];
    const int t = threadIdx.x;

    const int sl = t >> 3, dk0 = (t & 7) * 8;
    #pragma unroll
    for (int i = 0; i < 2; ++i) {
        const int s = sl + i * 32;
        u16x8 v = *(const u16x8*)(V + (size_t)(b * S + sb * 64 + s) * Dm + h * 64 + dk0);
        #pragma unroll
        for (int j = 0; j < 8; ++j)
            Lt[dk0 + j][s] = v[j];
    }
    __syncthreads();

    const int dk = t >> 2, scc = (t & 3) * 16;
    const size_t orow = ((size_t)((b * 16 + h) * 64 + dk)) * S + sb * 64;
    *(u16x8*)(Vt + orow + scc)     = *(const u16x8*)(&Lt[dk][scc]);
    *(u16x8*)(Vt + orow + scc + 8) = *(const u16x8*)(&Lt[dk][scc + 8]);
}

// ---------------------------------------------------------------------------
// Kernel 2: causal flash attention. 2048 SINGLE-WAVE blocks (64 threads),
// each owning one 32-row q-block (wave computes 2x 16-row groups). NO
// barriers: wave-private LDS ordered by lgkm/vmcnt. K double-buffered via
// global_load_lds with counted vmcnt (never drained to 0 mid-loop, T4).
// bid encoding keeps XCD locality and complementary per-CU load balance.
// LDS = 16KiB Ks + 4KiB Ps = 20480 B -> 8 blocks/CU (all 2048 co-resident).
// ---------------------------------------------------------------------------
__global__ __launch_bounds__(64, 2) void attn_fwd(
    const unsigned short* __restrict__ Qw, const unsigned short* __restrict__ Kw,
    const unsigned short* __restrict__ Vt, const int* __restrict__ amask,
    float* __restrict__ out)
{
    const int S = 1024, Dm = 1024;
    const int bid = blockIdx.x;
    const int m_  = bid >> 3;              // 0..255
    const int s_  = m_ >> 7;
    const int u_  = m_ & 127;
    const int p_  = u_ >> 3;               // 0..15
    const int bh  = (bid & 7) | ((u_ & 7) << 3);
    const int qb  = s_ ? (31 - p_) : p_;   // 32-row q-block index
    const int b = bh >> 4, h = bh & 15;
    const int lane = threadIdx.x;
    const int fr = lane & 15, fq = lane >> 4;

    __shared__ __align__(16) unsigned short Ks[2][4096];  // [64 rows][8 chunk slots], slot j holds chunk j^(row&7)
    __shared__ __align__(16) unsigned short Ps[32][64];   // XOR-swizzled: [row][col ^ ((row&7)<<3)]

    const size_t kwbase = (size_t)(b * S) * Dm + h * 64;
    const size_t vtbase = (size_t)((b * 16 + h) * 64) * S;

    const int srow = lane >> 3;    // 0..7
    const int schunk = lane & 7;

    const int q0 = qb * 32;
    const int nkt = (qb >> 1) + 1;   // 64-wide k-tiles

    // hoisted att_mask all-ones check
    bool mall;
    {
        const int4* ap = (const int4*)(amask + b * S);
        int acc = -1;
        #pragma unroll
        for (int c = 0; c < 4; ++c) {
            int4 v = ap[lane * 4 + c];
            acc &= (v.x != 0 && v.y != 0 && v.z != 0 && v.w != 0) ? -1 : 0;
        }
        mall = __all(acc != 0);
    }

    // Q fragments: 2 row-groups x 2 k-chunks
    bf16x8 qf[2][2];
    #pragma unroll
    for (int g = 0; g < 2; ++g) {
        const size_t qbp = (size_t)(b * S + q0 + g * 16 + fr) * Dm + h * 64;
        qf[g][0] = *(const bf16x8*)(Qw + qbp + fq * 8);
        qf[g][1] = *(const bf16x8*)(Qw + qbp + 32 + fq * 8);
    }

    f32x4 oacc[2][4] = {};
    float mrow[2][4], lpart[2][4];
    #pragma unroll
    for (int g = 0; g < 2; ++g)
        #pragma unroll
        for (int r = 0; r < 4; ++r) { mrow[g][r] = -3.0e38f; lpart[g][r] = 0.f; }

    // prologue: stage tile 0 into buf 0 (8 x 1KiB issues)
    #pragma unroll
    for (int i = 0; i < 8; ++i) {
        const int r_ = 8 * i + srow;
        const int cc = schunk ^ (r_ & 7);
        gload_lds16(Kw + kwbase + (size_t)r_ * Dm + cc * 8, &Ks[0][i * 512]);
    }

    int cur = 0;
    for (int kt = 0; kt < nkt; ++kt) {
        const int k0 = kt * 64;
        const bool stage = (kt + 1 < nkt);

        // stage next K tile (async; stays in flight across this tile's compute)
        if (stage) {
            #pragma unroll
            for (int i = 0; i < 8; ++i) {
                const int r_ = 8 * i + srow;
                const int cc = schunk ^ (r_ & 7);
                gload_lds16(Kw + kwbase + (size_t)(k0 + 64 + r_) * Dm + cc * 8,
                            &Ks[cur ^ 1][i * 512]);
            }
        }

        // V fragments direct from global (issue early, consumed by PV)
        bf16x8 vb[4][2];
        #pragma unroll
        for (int d = 0; d < 4; ++d)
            #pragma unroll
            for (int kc = 0; kc < 2; ++kc)
                vb[d][kc] = *(const bf16x8*)(Vt + vtbase + (size_t)(d * 16 + fr) * S + k0 + kc * 32 + fq * 8);

        // wait: K(t) staged; K(t+1) 8 + V(t) 8 may remain in flight
        if (stage) asm volatile("s_waitcnt vmcnt(16)" ::: "memory");
        else       asm volatile("s_waitcnt vmcnt(8)"  ::: "memory");
        __builtin_amdgcn_sched_barrier(0);

        // S = Q K^T from swizzled LDS (kb fragments shared by both row-groups)
        f32x4 sfr[2][4];
        __builtin_amdgcn_s_setprio(1);
        #pragma unroll
        for (int nf = 0; nf < 4; ++nf) {
            const int row = nf * 16 + fr;
            const bf16x8 kb0 = *(const bf16x8*)(&Ks[cur][row * 64 + ((fq ^ (row & 7)) * 8)]);
            const bf16x8 kb1 = *(const bf16x8*)(&Ks[cur][row * 64 + (((fq + 4) ^ (row & 7)) * 8)]);
            #pragma unroll
            for (int g = 0; g < 2; ++g) {
                f32x4 z = {};
                z = __builtin_amdgcn_mfma_f32_16x16x32_bf16(qf[g][0], kb0, z, 0, 0, 0);
                z = __builtin_amdgcn_mfma_f32_16x16x32_bf16(qf[g][1], kb1, z, 0, 0, 0);
                sfr[g][nf] = z;
            }
        }
        __builtin_amdgcn_s_setprio(0);

        if (!mall) {
            #pragma unroll
            for (int nf = 0; nf < 4; ++nf) {
                const float pen = (amask[b * S + k0 + nf * 16 + fr] == 0) ? -3.0e38f : 0.f;
                #pragma unroll
                for (int g = 0; g < 2; ++g)
                    #pragma unroll
                    for (int r = 0; r < 4; ++r) sfr[g][nf][r] += pen;
            }
        }
        // causal: only diagonal tile
        if (kt == nkt - 1) {
            #pragma unroll
            for (int nf = 0; nf < 4; ++nf) {
                const int kpos = k0 + nf * 16 + fr;
                #pragma unroll
                for (int g = 0; g < 2; ++g)
                    #pragma unroll
                    for (int r = 0; r < 4; ++r) {
                        const int qr = q0 + g * 16 + fq * 4 + r;
                        if (kpos > qr) sfr[g][nf][r] = -3.0e38f;
                    }
            }
        }

        // defer-max (THR=8 in exp2 domain)
        float plm[2][4];
        float grow = -3.0e38f;
        #pragma unroll
        for (int g = 0; g < 2; ++g)
            #pragma unroll
            for (int r = 0; r < 4; ++r) {
                plm[g][r] = fmaxf(fmaxf(sfr[g][0][r], sfr[g][1][r]),
                                  fmaxf(sfr[g][2][r], sfr[g][3][r]));
                grow = fmaxf(grow, plm[g][r] - mrow[g][r]);
            }
        if (!__all(grow <= 8.0f)) {
            #pragma unroll
            for (int g = 0; g < 2; ++g)
                #pragma unroll
                for (int r = 0; r < 4; ++r) {
                    float v = plm[g][r];
                    v = fmaxf(v, __shfl_xor(v, 1));
                    v = fmaxf(v, __shfl_xor(v, 2));
                    v = fmaxf(v, __shfl_xor(v, 4));
                    v = fmaxf(v, __shfl_xor(v, 8));
                    const float mn = fmaxf(mrow[g][r], v);
                    const float sc = fexp2(mrow[g][r] - mn);
                    mrow[g][r] = mn;
                    lpart[g][r] *= sc;
                    #pragma unroll
                    for (int d = 0; d < 4; ++d) oacc[g][d][r] *= sc;
                }
        }

        // p = exp2(s - m); per-lane partial sums; P -> swizzled LDS (bf16)
        #pragma unroll
        for (int g = 0; g < 2; ++g)
            #pragma unroll
            for (int nf = 0; nf < 4; ++nf)
                #pragma unroll
                for (int r = 0; r < 4; ++r) {
                    const float pv = fexp2(sfr[g][nf][r] - mrow[g][r]);
                    lpart[g][r] += pv;
                    const int rw = g * 16 + fq * 4 + r;
                    const int colx = (nf * 16 + fr) ^ ((rw & 7) << 3);
                    Ps[rw][colx] = f2bf(pv);
                }

        // O += P V (reads apply the same XOR; lgkm ordering is wave-local)
        __builtin_amdgcn_s_setprio(1);
        #pragma unroll
        for (int g = 0; g < 2; ++g) {
            const bf16x8 pa0 = *(const bf16x8*)(&Ps[g * 16 + fr][(fq ^ (fr & 7)) * 8]);
            const bf16x8 pa1 = *(const bf16x8*)(&Ps[g * 16 + fr][((fq + 4) ^ (fr & 7)) * 8]);
            #pragma unroll
            for (int d = 0; d < 4; ++d) {
                oacc[g][d] = __builtin_amdgcn_mfma_f32_16x16x32_bf16(pa0, vb[d][0], oacc[g][d], 0, 0, 0);
                oacc[g][d] = __builtin_amdgcn_mfma_f32_16x16x32_bf16(pa1, vb[d][1], oacc[g][d], 0, 0, 0);
            }
        }
        __builtin_amdgcn_s_setprio(0);

        cur ^= 1;
    }

    // epilogue
    #pragma unroll
    for (int g = 0; g < 2; ++g) {
        float inv[4];
        #pragma unroll
        for (int r = 0; r < 4; ++r) {
            float v = lpart[g][r];
            v += __shfl_xor(v, 1);
            v += __shfl_xor(v, 2);
            v += __shfl_xor(v, 4);
            v += __shfl_xor(v, 8);
            inv[r] = 1.0f / v;
        }
        #pragma unroll
        for (int d = 0; d < 4; ++d)
            #pragma unroll
            for (int r = 0; r < 4; ++r) {
                const int qr = q0 + g * 16 + fq * 4 + r;
                out[(size_t)(b * S + qr) * Dm + h * 64 + d * 16 + fr] = oacc[g][d][r] * inv[r];
            }
    }
}

// ---------------------------------------------------------------------------
extern "C" void kernel_launch(void* const* d_in, const int* in_sizes, int n_in,
                              void* d_out, int out_size, void* d_ws, size_t ws_size,
                              hipStream_t stream)
{
    const float* query = (const float*)d_in[0];
    const float* key_  = (const float*)d_in[1];
    const float* value = (const float*)d_in[2];
    const int*   amask = (const int*)d_in[3];
    const float* Wq = (const float*)d_in[4];
    const float* bq = (const float*)d_in[5];
    const float* Wk = (const float*)d_in[6];
    const float* bk = (const float*)d_in[7];
    const float* Wv = (const float*)d_in[8];
    const float* bv = (const float*)d_in[9];
    float* out = (float*)d_out;

    const size_t MD = (size_t)4096 * 1024;
    const size_t WD = (size_t)1024 * 1024;
    unsigned short* Qw  = (unsigned short*)d_ws;
    unsigned short* Kw  = Qw + MD;
    unsigned short* Vw  = Kw + MD;
    unsigned short* Vtw = Vw + MD;
    unsigned short* Wqb = Vtw + MD;
    unsigned short* Wkb = Wqb + WD;
    unsigned short* Wvb = Wkb + WD;

    // 1) weights fp32 -> bf16 (small)
    hipLaunchKernelGGL(cvt3, dim3(512, 3), dim3(256), 0, stream,
                       Wq, Wk, Wv, Wqb, Wkb, Wvb);
    // 2) projections with fused X conversion (depth-2 both paths)
    hipLaunchKernelGGL(gemm_bt, dim3(256, 3), dim3(256), 0, stream,
                       query, key_, value, Wqb, Wkb, Wvb, bq, bk, bv, Qw, Kw, Vw);
    // 3) V transpose
    hipLaunchKernelGGL(vtrans, dim3(16, 16, 4), dim3(256), 0, stream, Vw, Vtw);
    // 4) attention
    hipLaunchKernelGGL(attn_fwd, dim3(2048), dim3(64), 0, stream,
                       Qw, Kw, Vtw, amask, out);
}

// Round 20
// 84.967 us; speedup vs baseline: 1.0317x; 1.0317x over previous
//
#include <hip/hip_runtime.h>
#include <hip/hip_bf16.h>

using f32x4  = __attribute__((ext_vector_type(4))) float;
using bf16x8 = __attribute__((ext_vector_type(8))) __bf16;
using u16x8  = __attribute__((ext_vector_type(8))) unsigned short;

#define QSCALE 0.18033688f   // 0.125 * log2(e): scores pre-scaled into exp2 domain

static __device__ __forceinline__ unsigned short f2bf(float f) {
    unsigned u = __builtin_bit_cast(unsigned, f);
    u += 0x7FFF + ((u >> 16) & 1);   // RNE
    return (unsigned short)(u >> 16);
}

static __device__ __forceinline__ float fexp2(float x) {
    float r;
    asm("v_exp_f32 %0, %1" : "=v"(r) : "v"(x));
    return r;
}

static __device__ __forceinline__ u16x8 pk8(f32x4 a, f32x4 b) {
    u16x8 o;
    o[0] = __builtin_bit_cast(unsigned short, (__bf16)a.x);
    o[1] = __builtin_bit_cast(unsigned short, (__bf16)a.y);
    o[2] = __builtin_bit_cast(unsigned short, (__bf16)a.z);
    o[3] = __builtin_bit_cast(unsigned short, (__bf16)a.w);
    o[4] = __builtin_bit_cast(unsigned short, (__bf16)b.x);
    o[5] = __builtin_bit_cast(unsigned short, (__bf16)b.y);
    o[6] = __builtin_bit_cast(unsigned short, (__bf16)b.z);
    o[7] = __builtin_bit_cast(unsigned short, (__bf16)b.w);
    return o;
}

static __device__ __forceinline__ void gload_lds16(const unsigned short* g, unsigned short* l) {
    __builtin_amdgcn_global_load_lds(
        (const __attribute__((address_space(1))) unsigned int*)g,
        (__attribute__((address_space(3))) unsigned int*)l, 16, 0, 0);
}

// ---------------------------------------------------------------------------
// Kernel 0: fp32 -> bf16 convert — WEIGHTS ONLY.
// ---------------------------------------------------------------------------
__global__ __launch_bounds__(256) void cvt3(
    const float* __restrict__ s0, const float* __restrict__ s1, const float* __restrict__ s2,
    unsigned short* __restrict__ d0, unsigned short* __restrict__ d1, unsigned short* __restrict__ d2)
{
    const int y = blockIdx.y;
    const float* s = y == 0 ? s0 : y == 1 ? s1 : s2;
    unsigned short* d = y == 0 ? d0 : y == 1 ? d1 : d2;
    const int n = 1024 * 1024;
    const int stride = gridDim.x * 256 * 8;
    for (int i = (blockIdx.x * 256 + threadIdx.x) * 8; i < n; i += stride) {
        f32x4 a = *(const f32x4*)(s + i);
        f32x4 b = *(const f32x4*)(s + i + 4);
        *(u16x8*)(d + i) = pk8(a, b);
    }
}

// ---------------------------------------------------------------------------
// Kernel 1 (fused fp32->bf16 A-path, SINGLE-BARRIER loop):
// Y = X_fp32 @ W_bf16^T + bias. 128x128 tile, 4 waves, BK=32.
// As double-buffered (16 KiB), Bs QUAD-buffered (32 KiB). Per iteration j:
//   T0 (j>=1): cvt a(j) regs (loaded S1(j-1)) -> ds_write As[j&1].
//       The compiler's wait for a(j) FIFO-retires B(j) (issued S2(j-2),
//       older) -> B gets 2 iterations of latency cover for free.
//   S1 load a(j+1) fp32 -> regs
//   S2 issue B(j+2) global_load_lds -> Bs[(j+2)&3]
//   S4 lgkmcnt(0) + ONE s_barrier
//   S5 ds_read frags + 16 MFMA
// Hazard audit (skew <= 1 barrier): fast wave writes As[(j+1)&1] /
// Bs[(j+3)&3]; slowest reader uses As[j&1] / Bs[j&3] — always disjoint.
// which = blockIdx.y; which==0 (Q) xQSCALE. XCD-chunked block swizzle.
// ---------------------------------------------------------------------------
__global__ __launch_bounds__(256) void gemm_bt(
    const float* __restrict__ X0, const float* __restrict__ X1, const float* __restrict__ X2,
    const unsigned short* __restrict__ B0, const unsigned short* __restrict__ B1, const unsigned short* __restrict__ B2,
    const float* __restrict__ b0, const float* __restrict__ b1, const float* __restrict__ b2,
    unsigned short* __restrict__ O0, unsigned short* __restrict__ O1, unsigned short* __restrict__ O2)
{
    const int N = 1024, K = 1024;
    const int which = blockIdx.y;
    const float* X = which == 0 ? X0 : (which == 1 ? X1 : X2);
    const unsigned short* B = which == 0 ? B0 : (which == 1 ? B1 : B2);
    const float* bias = which == 0 ? b0 : (which == 1 ? b1 : b2);
    unsigned short* O = which == 0 ? O0 : (which == 1 ? O1 : O2);

    const int xs = (blockIdx.x & 7) * 32 + (blockIdx.x >> 3);   // bijective XCD chunking
    const int bm = xs >> 3;
    const int bn = xs & 7;
    const int row0 = bm * 128, col0 = bn * 128;

    __shared__ __align__(16) unsigned short As[2 * 4096];
    __shared__ __align__(16) unsigned short Bs[4 * 4096];

    const int t = threadIdx.x;
    const int lane = t & 63;
    const int wave = t >> 6;
    const int wr = (wave >> 1) * 64, wc = (wave & 1) * 64;
    const int fr = lane & 15;
    const int fq = lane >> 4;

    f32x4 acc[4][4] = {};

    const int r0s = t >> 2, k0s = (t & 3) * 8;
    const int r1s = (t + 256) >> 2;
    const int dB0 = (wave * 64) * 8;
    const int dB1 = (256 + wave * 64) * 8;

    const float* Xa0 = X + (size_t)(row0 + r0s) * K + k0s;
    const float* Xa1 = X + (size_t)(row0 + r1s) * K + k0s;
    const unsigned short* Bb0 = B + (size_t)(col0 + r0s) * K + k0s;
    const unsigned short* Bb1 = B + (size_t)(col0 + r1s) * K + k0s;
    unsigned short* wA0 = &As[r0s * 32 + k0s];
    unsigned short* wA1 = &As[r1s * 32 + k0s];

    // prologue: a(0) load+write As[0]; B(0)->Bs[0], B(1)->Bs[1]
    {
        f32x4 p0 = *(const f32x4*)(Xa0);
        f32x4 p1 = *(const f32x4*)(Xa0 + 4);
        f32x4 p2 = *(const f32x4*)(Xa1);
        f32x4 p3 = *(const f32x4*)(Xa1 + 4);
        gload_lds16(Bb0, &Bs[dB0]);
        gload_lds16(Bb1, &Bs[dB1]);
        gload_lds16(Bb0 + 32, &Bs[4096 + dB0]);
        gload_lds16(Bb1 + 32, &Bs[4096 + dB1]);
        *(u16x8*)(wA0) = pk8(p0, p1);    // compiler waits p-regs (B0/B1 newer: stay)
        *(u16x8*)(wA1) = pk8(p2, p3);
    }

    f32x4 rW0, rW1, rW2, rW3;   // a(j) at loop top (loaded at S1 of j-1)
    for (int j = 0; j < 32; ++j) {
        // T0: write a(j) into As[j&1]; implicit wait retires B(j) too (FIFO)
        if (j >= 1) {
            const int aOff = (j & 1) * 4096;
            *(u16x8*)(wA0 + aOff) = pk8(rW0, rW1);
            *(u16x8*)(wA1 + aOff) = pk8(rW2, rW3);
        }
        f32x4 rT0, rT1, rT2, rT3;
        if (j + 1 < 32) {
            // S1: a(j+1) -> regs
            const int kn1 = (j + 1) * 32;
            rT0 = *(const f32x4*)(Xa0 + kn1);
            rT1 = *(const f32x4*)(Xa0 + kn1 + 4);
            rT2 = *(const f32x4*)(Xa1 + kn1);
            rT3 = *(const f32x4*)(Xa1 + kn1 + 4);
        }
        if (j + 2 < 32) {
            // S2: B(j+2) -> Bs[(j+2)&3]
            const int kn2 = (j + 2) * 32;
            gload_lds16(Bb0 + kn2, &Bs[((j + 2) & 3) * 4096 + dB0]);
            gload_lds16(Bb1 + kn2, &Bs[((j + 2) & 3) * 4096 + dB1]);
        }
        if (j == 0) {
            // only B(1)2 + a(1)4 + B(2)2 = 8 are newer than B(0)
            asm volatile("s_waitcnt vmcnt(8)" ::: "memory");
            __builtin_amdgcn_sched_barrier(0);
        }
        // S4: single barrier per iteration
        asm volatile("s_waitcnt lgkmcnt(0)" ::: "memory");
        __builtin_amdgcn_s_barrier();

        // S5: compute tile j
        const int aOff = (j & 1) * 4096;
        const int bOff = (j & 3) * 4096;
        bf16x8 af[4], bfr[4];
        #pragma unroll
        for (int m = 0; m < 4; ++m)
            af[m] = *(const bf16x8*)(&As[aOff + (wr + m * 16 + fr) * 32 + fq * 8]);
        #pragma unroll
        for (int n = 0; n < 4; ++n)
            bfr[n] = *(const bf16x8*)(&Bs[bOff + (wc + n * 16 + fr) * 32 + fq * 8]);
        __builtin_amdgcn_s_setprio(1);
        #pragma unroll
        for (int m = 0; m < 4; ++m)
            #pragma unroll
            for (int n = 0; n < 4; ++n)
                acc[m][n] = __builtin_amdgcn_mfma_f32_16x16x32_bf16(af[m], bfr[n], acc[m][n], 0, 0, 0);
        __builtin_amdgcn_s_setprio(0);

        rW0 = rT0; rW1 = rT1; rW2 = rT2; rW3 = rT3;
    }

    const float sc = (which == 0) ? QSCALE : 1.0f;
    #pragma unroll
    for (int n = 0; n < 4; ++n) {
        const int col = col0 + wc + n * 16 + fr;
        const float bv = bias[col];
        #pragma unroll
        for (int m = 0; m < 4; ++m) {
            #pragma unroll
            for (int r = 0; r < 4; ++r) {
                const int row = row0 + wr + m * 16 + fq * 4 + r;
                O[(size_t)row * N + col] = f2bf((acc[m][n][r] + bv) * sc);
            }
        }
    }
}

// ---------------------------------------------------------------------------
// Kernel 1b: V[b*S+s][h*64+dk] -> Vt[(b*16+h)*64+dk][s]. LDS 64x72 tile.
// ---------------------------------------------------------------------------
__global__ __launch_bounds__(256) void vtrans(
    const unsigned short* __restrict__ V, unsigned short* __restrict__ Vt)
{
    const int S = 1024, Dm = 1024;
    const int sb = blockIdx.x;
    const int h = blockIdx.y, b = blockIdx.z;
    __shared__ __align__(16) unsigned short Lt[64][72];
    const int t = threadIdx.x;

    const int sl = t >> 3, dk0 = (t & 7) * 8;
    #pragma unroll
    for (int i = 0; i < 2; ++i) {
        const int s = sl + i * 32;
        u16x8 v = *(const u16x8*)(V + (size_t)(b * S + sb * 64 + s) * Dm + h * 64 + dk0);
        #pragma unroll
        for (int j = 0; j < 8; ++j)
            Lt[dk0 + j][s] = v[j];
    }
    __syncthreads();

    const int dk = t >> 2, scc = (t & 3) * 16;
    const size_t orow = ((size_t)((b * 16 + h) * 64 + dk)) * S + sb * 64;
    *(u16x8*)(Vt + orow + scc)     = *(const u16x8*)(&Lt[dk][scc]);
    *(u16x8*)(Vt + orow + scc + 8) = *(const u16x8*)(&Lt[dk][scc + 8]);
}

// ---------------------------------------------------------------------------
// Kernel 2: causal flash attention. 2048 SINGLE-WAVE blocks (64 threads),
// each owning one 32-row q-block (wave computes 2x 16-row groups). NO
// barriers: wave-private LDS ordered by lgkm/vmcnt. K double-buffered via
// global_load_lds with counted vmcnt (never drained to 0 mid-loop, T4).
// bid encoding keeps XCD locality and complementary per-CU load balance.
// LDS = 16KiB Ks + 4KiB Ps = 20480 B -> 8 blocks/CU (all 2048 co-resident).
// ---------------------------------------------------------------------------
__global__ __launch_bounds__(64, 2) void attn_fwd(
    const unsigned short* __restrict__ Qw, const unsigned short* __restrict__ Kw,
    const unsigned short* __restrict__ Vt, const int* __restrict__ amask,
    float* __restrict__ out)
{
    const int S = 1024, Dm = 1024;
    const int bid = blockIdx.x;
    const int m_  = bid >> 3;              // 0..255
    const int s_  = m_ >> 7;
    const int u_  = m_ & 127;
    const int p_  = u_ >> 3;               // 0..15
    const int bh  = (bid & 7) | ((u_ & 7) << 3);
    const int qb  = s_ ? (31 - p_) : p_;   // 32-row q-block index
    const int b = bh >> 4, h = bh & 15;
    const int lane = threadIdx.x;
    const int fr = lane & 15, fq = lane >> 4;

    __shared__ __align__(16) unsigned short Ks[2][4096];  // [64 rows][8 chunk slots], slot j holds chunk j^(row&7)
    __shared__ __align__(16) unsigned short Ps[32][64];   // XOR-swizzled: [row][col ^ ((row&7)<<3)]

    const size_t kwbase = (size_t)(b * S) * Dm + h * 64;
    const size_t vtbase = (size_t)((b * 16 + h) * 64) * S;

    const int srow = lane >> 3;    // 0..7
    const int schunk = lane & 7;

    const int q0 = qb * 32;
    const int nkt = (qb >> 1) + 1;   // 64-wide k-tiles

    // hoisted att_mask all-ones check
    bool mall;
    {
        const int4* ap = (const int4*)(amask + b * S);
        int acc = -1;
        #pragma unroll
        for (int c = 0; c < 4; ++c) {
            int4 v = ap[lane * 4 + c];
            acc &= (v.x != 0 && v.y != 0 && v.z != 0 && v.w != 0) ? -1 : 0;
        }
        mall = __all(acc != 0);
    }

    // Q fragments: 2 row-groups x 2 k-chunks
    bf16x8 qf[2][2];
    #pragma unroll
    for (int g = 0; g < 2; ++g) {
        const size_t qbp = (size_t)(b * S + q0 + g * 16 + fr) * Dm + h * 64;
        qf[g][0] = *(const bf16x8*)(Qw + qbp + fq * 8);
        qf[g][1] = *(const bf16x8*)(Qw + qbp + 32 + fq * 8);
    }

    f32x4 oacc[2][4] = {};
    float mrow[2][4], lpart[2][4];
    #pragma unroll
    for (int g = 0; g < 2; ++g)
        #pragma unroll
        for (int r = 0; r < 4; ++r) { mrow[g][r] = -3.0e38f; lpart[g][r] = 0.f; }

    // prologue: stage tile 0 into buf 0 (8 x 1KiB issues)
    #pragma unroll
    for (int i = 0; i < 8; ++i) {
        const int r_ = 8 * i + srow;
        const int cc = schunk ^ (r_ & 7);
        gload_lds16(Kw + kwbase + (size_t)r_ * Dm + cc * 8, &Ks[0][i * 512]);
    }

    int cur = 0;
    for (int kt = 0; kt < nkt; ++kt) {
        const int k0 = kt * 64;
        const bool stage = (kt + 1 < nkt);

        // stage next K tile (async; stays in flight across this tile's compute)
        if (stage) {
            #pragma unroll
            for (int i = 0; i < 8; ++i) {
                const int r_ = 8 * i + srow;
                const int cc = schunk ^ (r_ & 7);
                gload_lds16(Kw + kwbase + (size_t)(k0 + 64 + r_) * Dm + cc * 8,
                            &Ks[cur ^ 1][i * 512]);
            }
        }

        // V fragments direct from global (issue early, consumed by PV)
        bf16x8 vb[4][2];
        #pragma unroll
        for (int d = 0; d < 4; ++d)
            #pragma unroll
            for (int kc = 0; kc < 2; ++kc)
                vb[d][kc] = *(const bf16x8*)(Vt + vtbase + (size_t)(d * 16 + fr) * S + k0 + kc * 32 + fq * 8);

        // wait: K(t) staged; K(t+1) 8 + V(t) 8 may remain in flight
        if (stage) asm volatile("s_waitcnt vmcnt(16)" ::: "memory");
        else       asm volatile("s_waitcnt vmcnt(8)"  ::: "memory");
        __builtin_amdgcn_sched_barrier(0);

        // S = Q K^T from swizzled LDS (kb fragments shared by both row-groups)
        f32x4 sfr[2][4];
        __builtin_amdgcn_s_setprio(1);
        #pragma unroll
        for (int nf = 0; nf < 4; ++nf) {
            const int row = nf * 16 + fr;
            const bf16x8 kb0 = *(const bf16x8*)(&Ks[cur][row * 64 + ((fq ^ (row & 7)) * 8)]);
            const bf16x8 kb1 = *(const bf16x8*)(&Ks[cur][row * 64 + (((fq + 4) ^ (row & 7)) * 8)]);
            #pragma unroll
            for (int g = 0; g < 2; ++g) {
                f32x4 z = {};
                z = __builtin_amdgcn_mfma_f32_16x16x32_bf16(qf[g][0], kb0, z, 0, 0, 0);
                z = __builtin_amdgcn_mfma_f32_16x16x32_bf16(qf[g][1], kb1, z, 0, 0, 0);
                sfr[g][nf] = z;
            }
        }
        __builtin_amdgcn_s_setprio(0);

        if (!mall) {
            #pragma unroll
            for (int nf = 0; nf < 4; ++nf) {
                const float pen = (amask[b * S + k0 + nf * 16 + fr] == 0) ? -3.0e38f : 0.f;
                #pragma unroll
                for (int g = 0; g < 2; ++g)
                    #pragma unroll
                    for (int r = 0; r < 4; ++r) sfr[g][nf][r] += pen;
            }
        }
        // causal: only diagonal tile
        if (kt == nkt - 1) {
            #pragma unroll
            for (int nf = 0; nf < 4; ++nf) {
                const int kpos = k0 + nf * 16 + fr;
                #pragma unroll
                for (int g = 0; g < 2; ++g)
                    #pragma unroll
                    for (int r = 0; r < 4; ++r) {
                        const int qr = q0 + g * 16 + fq * 4 + r;
                        if (kpos > qr) sfr[g][nf][r] = -3.0e38f;
                    }
            }
        }

        // defer-max (THR=8 in exp2 domain)
        float plm[2][4];
        float grow = -3.0e38f;
        #pragma unroll
        for (int g = 0; g < 2; ++g)
            #pragma unroll
            for (int r = 0; r < 4; ++r) {
                plm[g][r] = fmaxf(fmaxf(sfr[g][0][r], sfr[g][1][r]),
                                  fmaxf(sfr[g][2][r], sfr[g][3][r]));
                grow = fmaxf(grow, plm[g][r] - mrow[g][r]);
            }
        if (!__all(grow <= 8.0f)) {
            #pragma unroll
            for (int g = 0; g < 2; ++g)
                #pragma unroll
                for (int r = 0; r < 4; ++r) {
                    float v = plm[g][r];
                    v = fmaxf(v, __shfl_xor(v, 1));
                    v = fmaxf(v, __shfl_xor(v, 2));
                    v = fmaxf(v, __shfl_xor(v, 4));
                    v = fmaxf(v, __shfl_xor(v, 8));
                    const float mn = fmaxf(mrow[g][r], v);
                    const float sc = fexp2(mrow[g][r] - mn);
                    mrow[g][r] = mn;
                    lpart[g][r] *= sc;
                    #pragma unroll
                    for (int d = 0; d < 4; ++d) oacc[g][d][r] *= sc;
                }
        }

        // p = exp2(s - m); per-lane partial sums; P -> swizzled LDS (bf16)
        #pragma unroll
        for (int g = 0; g < 2; ++g)
            #pragma unroll
            for (int nf = 0; nf < 4; ++nf)
                #pragma unroll
                for (int r = 0; r < 4; ++r) {
                    const float pv = fexp2(sfr[g][nf][r] - mrow[g][r]);
                    lpart[g][r] += pv;
                    const int rw = g * 16 + fq * 4 + r;
                    const int colx = (nf * 16 + fr) ^ ((rw & 7) << 3);
                    Ps[rw][colx] = f2bf(pv);
                }

        // O += P V (reads apply the same XOR; lgkm ordering is wave-local)
        __builtin_amdgcn_s_setprio(1);
        #pragma unroll
        for (int g = 0; g < 2; ++g) {
            const bf16x8 pa0 = *(const bf16x8*)(&Ps[g * 16 + fr][(fq ^ (fr & 7)) * 8]);
            const bf16x8 pa1 = *(const bf16x8*)(&Ps[g * 16 + fr][((fq + 4) ^ (fr & 7)) * 8]);
            #pragma unroll
            for (int d = 0; d < 4; ++d) {
                oacc[g][d] = __builtin_amdgcn_mfma_f32_16x16x32_bf16(pa0, vb[d][0], oacc[g][d], 0, 0, 0);
                oacc[g][d] = __builtin_amdgcn_mfma_f32_16x16x32_bf16(pa1, vb[d][1], oacc[g][d], 0, 0, 0);
            }
        }
        __builtin_amdgcn_s_setprio(0);

        cur ^= 1;
    }

    // epilogue
    #pragma unroll
    for (int g = 0; g < 2; ++g) {
        float inv[4];
        #pragma unroll
        for (int r = 0; r < 4; ++r) {
            float v = lpart[g][r];
            v += __shfl_xor(v, 1);
            v += __shfl_xor(v, 2);
            v += __shfl_xor(v, 4);
            v += __shfl_xor(v, 8);
            inv[r] = 1.0f / v;
        }
        #pragma unroll
        for (int d = 0; d < 4; ++d)
            #pragma unroll
            for (int r = 0; r < 4; ++r) {
                const int qr = q0 + g * 16 + fq * 4 + r;
                out[(size_t)(b * S + qr) * Dm + h * 64 + d * 16 + fr] = oacc[g][d][r] * inv[r];
            }
    }
}

// ---------------------------------------------------------------------------
extern "C" void kernel_launch(void* const* d_in, const int* in_sizes, int n_in,
                              void* d_out, int out_size, void* d_ws, size_t ws_size,
                              hipStream_t stream)
{
    const float* query = (const float*)d_in[0];
    const float* key_  = (const float*)d_in[1];
    const float* value = (const float*)d_in[2];
    const int*   amask = (const int*)d_in[3];
    const float* Wq = (const float*)d_in[4];
    const float* bq = (const float*)d_in[5];
    const float* Wk = (const float*)d_in[6];
    const float* bk = (const float*)d_in[7];
    const float* Wv = (const float*)d_in[8];
    const float* bv = (const float*)d_in[9];
    float* out = (float*)d_out;

    const size_t MD = (size_t)4096 * 1024;
    const size_t WD = (size_t)1024 * 1024;
    unsigned short* Qw  = (unsigned short*)d_ws;
    unsigned short* Kw  = Qw + MD;
    unsigned short* Vw  = Kw + MD;
    unsigned short* Vtw = Vw + MD;
    unsigned short* Wqb = Vtw + MD;
    unsigned short* Wkb = Wqb + WD;
    unsigned short* Wvb = Wkb + WD;

    // 1) weights fp32 -> bf16 (small)
    hipLaunchKernelGGL(cvt3, dim3(512, 3), dim3(256), 0, stream,
                       Wq, Wk, Wv, Wqb, Wkb, Wvb);
    // 2) projections with fused X conversion (single-barrier loop)
    hipLaunchKernelGGL(gemm_bt, dim3(256, 3), dim3(256), 0, stream,
                       query, key_, value, Wqb, Wkb, Wvb, bq, bk, bv, Qw, Kw, Vw);
    // 3) V transpose
    hipLaunchKernelGGL(vtrans, dim3(16, 16, 4), dim3(256), 0, stream, Vw, Vtw);
    // 4) attention
    hipLaunchKernelGGL(attn_fwd, dim3(2048), dim3(64), 0, stream,
                       Qw, Kw, Vtw, amask, out);
}